// Round 1
// baseline (72.271 us; speedup 1.0000x reference)
//
#include <hip/hip_runtime.h>
#include <float.h>

#define NUM_HEADS    32
#define NUM_KV_HEADS 8
#define HEAD_SIZE    128
#define Q_PER_KV     4
#define BLOCK_SZ     16
#define MAX_BLOCKS   128
#define MAX_CTX      2048
#define SCALE        0.08838834764831845f

typedef float v4f __attribute__((ext_vector_type(4)));

// One workgroup per (kv_head, batch). 512 threads = 8 waves.
__global__ __launch_bounds__(512, 2)
void paged_attn_kernel(const float* __restrict__ query,
                       const float* __restrict__ k_new,
                       const float* __restrict__ v_new,
                       const float* __restrict__ key_cache,
                       const float* __restrict__ value_cache,
                       const int* __restrict__ block_tables,
                       const int* __restrict__ context_lens,
                       float* __restrict__ out) {
    const int h   = blockIdx.x;   // kv head 0..7
    const int b   = blockIdx.y;   // batch  0..31
    const int tid = threadIdx.x;  // 0..511

    __shared__ float q_lds[Q_PER_KV * HEAD_SIZE];   // 2 KB (pre-scaled by SCALE)
    __shared__ float s_lds[Q_PER_KV * MAX_CTX];     // 32 KB scores -> probs
    __shared__ float red_lds[4 * Q_PER_KV * HEAD_SIZE]; // 8 KB partial PV
    __shared__ float inv_lds[Q_PER_KV];

    const int ctx  = context_lens[b];
    const int nb   = (ctx + BLOCK_SZ - 1) / BLOCK_SZ;  // valid blocks
    const int last = ctx - 1;                           // logical pos of new token

    // ---- stage Q into LDS, folding in SCALE ----
    {
        const int qh = tid >> 7, d = tid & 127;
        q_lds[tid] = query[((size_t)b * NUM_HEADS + h * Q_PER_KV + qh) * HEAD_SIZE + d] * SCALE;
    }
    __syncthreads();

    // ---- pass 1: scores = (Q*SCALE) . K  for all tokens ----
    {
        const int bi = tid >> 2;   // block index 0..127
        const int o  = tid & 3;    // which float4 of the 16-token row
        if (bi < nb) {
            const int phys = block_tables[b * MAX_BLOCKS + bi];
            const v4f* kp = reinterpret_cast<const v4f*>(key_cache) +
                            ((size_t)phys * NUM_KV_HEADS + h) * (HEAD_SIZE * BLOCK_SZ / 4);
            const v4f* q4 = reinterpret_cast<const v4f*>(q_lds);
            v4f acc[Q_PER_KV];
            #pragma unroll
            for (int qh = 0; qh < Q_PER_KV; ++qh) acc[qh] = (v4f)0.f;

            #pragma unroll 4
            for (int d4 = 0; d4 < HEAD_SIZE / 4; ++d4) {
                v4f k[4];
                #pragma unroll
                for (int dd = 0; dd < 4; ++dd) k[dd] = kp[d4 * 16 + dd * 4 + o];
                #pragma unroll
                for (int qh = 0; qh < Q_PER_KV; ++qh) {
                    v4f qv = q4[qh * (HEAD_SIZE / 4) + d4];
                    #pragma unroll
                    for (int dd = 0; dd < 4; ++dd) acc[qh] += qv[dd] * k[dd];
                }
            }
            const int t0 = bi * BLOCK_SZ + o * 4;
            #pragma unroll
            for (int qh = 0; qh < Q_PER_KV; ++qh) {
                v4f sv;
                #pragma unroll
                for (int j = 0; j < 4; ++j)
                    sv[j] = (t0 + j < ctx) ? acc[qh][j] : -FLT_MAX;
                *reinterpret_cast<v4f*>(&s_lds[qh * MAX_CTX + t0]) = sv;
            }
        }
    }
    __syncthreads();

    // ---- override score at logical position `last` with k_new (cache slot is stale) ----
    if (tid < 4 * 64) {
        const int w = tid >> 6, lane = tid & 63;
        const float* kn = k_new + ((size_t)b * NUM_KV_HEADS + h) * HEAD_SIZE;
        float v = q_lds[w * HEAD_SIZE + lane] * kn[lane] +
                  q_lds[w * HEAD_SIZE + lane + 64] * kn[lane + 64];
        #pragma unroll
        for (int off = 32; off; off >>= 1) v += __shfl_xor(v, off);
        if (lane == 0) s_lds[w * MAX_CTX + last] = v;
    }
    __syncthreads();

    // ---- softmax: wave w handles q-head w ----
    if (tid < 4 * 64) {
        const int w = tid >> 6, lane = tid & 63;
        const int T = nb * BLOCK_SZ;
        float m = -FLT_MAX;
        for (int t = lane; t < T; t += 64) m = fmaxf(m, s_lds[w * MAX_CTX + t]);
        #pragma unroll
        for (int off = 32; off; off >>= 1) m = fmaxf(m, __shfl_xor(m, off));
        float sum = 0.f;
        for (int t = lane; t < T; t += 64) {
            float e = __expf(s_lds[w * MAX_CTX + t] - m);
            s_lds[w * MAX_CTX + t] = e;
            sum += e;
        }
        #pragma unroll
        for (int off = 32; off; off >>= 1) sum += __shfl_xor(sum, off);
        if (lane == 0) inv_lds[w] = 1.0f / sum;
    }
    __syncthreads();

    // ---- grab p at `last`, then zero it (its cached V is stale; add v_new later) ----
    float pl[Q_PER_KV];
    #pragma unroll
    for (int qh = 0; qh < Q_PER_KV; ++qh) pl[qh] = s_lds[qh * MAX_CTX + last];
    __syncthreads();
    if (tid < Q_PER_KV) s_lds[tid * MAX_CTX + last] = 0.f;
    __syncthreads();

    // ---- pass 2: O = P . V  (thread = dim d, 4-way token split) ----
    {
        const int d   = tid & 127;
        const int seg = tid >> 7;  // 0..3
        float acc[Q_PER_KV] = {0.f, 0.f, 0.f, 0.f};

        for (int bi = seg; bi < nb; bi += 4) {
            const int phys = block_tables[b * MAX_BLOCKS + bi];
            const v4f* vp = reinterpret_cast<const v4f*>(value_cache) +
                            ((size_t)phys * NUM_KV_HEADS + h) * (HEAD_SIZE * BLOCK_SZ / 4);
            v4f vv[4];
            #pragma unroll
            for (int j = 0; j < 4; ++j) vv[j] = vp[d * 4 + j];
            #pragma unroll
            for (int qh = 0; qh < Q_PER_KV; ++qh) {
                const v4f* pq = reinterpret_cast<const v4f*>(&s_lds[qh * MAX_CTX + bi * BLOCK_SZ]);
                #pragma unroll
                for (int j = 0; j < 4; ++j) {
                    v4f p = pq[j];
                    acc[qh] += p[0] * vv[j][0] + p[1] * vv[j][1] +
                               p[2] * vv[j][2] + p[3] * vv[j][3];
                }
            }
        }

        // new token's V contribution (seg 0 only, exactly once per d)
        if (seg == 0) {
            const float vn = v_new[((size_t)b * NUM_KV_HEADS + h) * HEAD_SIZE + d];
            #pragma unroll
            for (int qh = 0; qh < Q_PER_KV; ++qh) acc[qh] += pl[qh] * vn;
        }

        #pragma unroll
        for (int qh = 0; qh < Q_PER_KV; ++qh)
            red_lds[(seg * Q_PER_KV + qh) * HEAD_SIZE + d] = acc[qh];
    }
    __syncthreads();

    // ---- reduce 4 segments, scale by 1/sum, store ----
    {
        const int qh = tid >> 7, d = tid & 127;
        float r = red_lds[(0 * Q_PER_KV + qh) * HEAD_SIZE + d] +
                  red_lds[(1 * Q_PER_KV + qh) * HEAD_SIZE + d] +
                  red_lds[(2 * Q_PER_KV + qh) * HEAD_SIZE + d] +
                  red_lds[(3 * Q_PER_KV + qh) * HEAD_SIZE + d];
        out[((size_t)b * NUM_HEADS + h * Q_PER_KV + qh) * HEAD_SIZE + d] = r * inv_lds[qh];
    }
}

extern "C" void kernel_launch(void* const* d_in, const int* in_sizes, int n_in,
                              void* d_out, int out_size, void* d_ws, size_t ws_size,
                              hipStream_t stream) {
    const float* query       = (const float*)d_in[0];
    const float* k_new       = (const float*)d_in[1];
    const float* v_new       = (const float*)d_in[2];
    const float* key_cache   = (const float*)d_in[3];
    const float* value_cache = (const float*)d_in[4];
    const int*   block_tables  = (const int*)d_in[5];
    const int*   context_lens  = (const int*)d_in[6];
    // d_in[7] = slot_mapping: not needed — the new token is logical position ctx-1.
    float* out = (float*)d_out;

    const int batch = in_sizes[6];  // context_lens count
    dim3 grid(NUM_KV_HEADS, batch);
    paged_attn_kernel<<<grid, 512, 0, stream>>>(query, k_new, v_new,
                                                key_cache, value_cache,
                                                block_tables, context_lens, out);
}

// Round 2
// 65.677 us; speedup vs baseline: 1.1004x; 1.1004x over previous
//
#include <hip/hip_runtime.h>
#include <float.h>

#define NUM_HEADS    32
#define NUM_KV_HEADS 8
#define HEAD_SIZE    128
#define Q_PER_KV     4
#define BLOCK_SZ     16
#define MAX_BLOCKS   128
#define MAX_CTX      2048
#define SCALE        0.08838834764831845f

#define CHUNK_BLOCKS 16                      // cache blocks per chunk
#define CHUNK_TOK    (CHUNK_BLOCKS * BLOCK_SZ)  // 256 tokens
#define NCHUNK       (MAX_BLOCKS / CHUNK_BLOCKS) // 8
#define WS_STRIDE    (2 * Q_PER_KV + Q_PER_KV * HEAD_SIZE)  // 520 floats per (b,h,c)

typedef float v4f __attribute__((ext_vector_type(4)));

// ---------------- kernel 1: per-chunk partial attention ----------------
// grid (NUM_KV_HEADS, BATCH, NCHUNK), 64 threads (1 wave).
__global__ __launch_bounds__(64, 8)
void paged_attn_chunk(const float* __restrict__ query,
                      const float* __restrict__ key_cache,
                      const float* __restrict__ value_cache,
                      const int* __restrict__ block_tables,
                      const int* __restrict__ context_lens,
                      float* __restrict__ ws) {
    const int h   = blockIdx.x;
    const int b   = blockIdx.y;
    const int c   = blockIdx.z;
    const int tid = threadIdx.x;  // 0..63

    const int ctx  = context_lens[b];
    const int nb   = (ctx + BLOCK_SZ - 1) / BLOCK_SZ;
    const int cb   = c * CHUNK_BLOCKS;          // first cache block of chunk
    if (cb >= nb) return;                        // empty chunk: reducer skips it
    const int last = ctx - 1;                    // stale slot -> masked out here

    __shared__ float q_lds[Q_PER_KV * HEAD_SIZE];   // 2 KB, pre-scaled
    __shared__ float s_lds[Q_PER_KV * CHUNK_TOK];   // 4 KB scores -> probs
    __shared__ float ml_lds[2 * Q_PER_KV];

    // stage Q (512 floats) with float4
    {
        const v4f* qg = reinterpret_cast<const v4f*>(
            query + ((size_t)b * NUM_HEADS + h * Q_PER_KV) * HEAD_SIZE);
        v4f* ql = reinterpret_cast<v4f*>(q_lds);
        ql[tid]      = qg[tid]      * SCALE;
        ql[tid + 64] = qg[tid + 64] * SCALE;
    }
    __syncthreads();

    // ---- scores: thread = (local block bi, float4-slice o) ----
    {
        const int bil = tid >> 2;            // 0..15
        const int o   = tid & 3;
        const int bi  = cb + bil;
        const int t0  = bil * BLOCK_SZ + o * 4;   // chunk-local token of lane's 4
        if (bi < nb) {
            const int phys = block_tables[b * MAX_BLOCKS + bi];
            const v4f* kp = reinterpret_cast<const v4f*>(key_cache) +
                            ((size_t)phys * NUM_KV_HEADS + h) * (HEAD_SIZE * BLOCK_SZ / 4);
            const v4f* q4 = reinterpret_cast<const v4f*>(q_lds);
            v4f acc[Q_PER_KV];
            #pragma unroll
            for (int qh = 0; qh < Q_PER_KV; ++qh) acc[qh] = (v4f)0.f;
            #pragma unroll 4
            for (int d4 = 0; d4 < HEAD_SIZE / 4; ++d4) {
                v4f k[4];
                #pragma unroll
                for (int dd = 0; dd < 4; ++dd) k[dd] = kp[d4 * 16 + dd * 4 + o];
                #pragma unroll
                for (int qh = 0; qh < Q_PER_KV; ++qh) {
                    v4f qv = q4[qh * (HEAD_SIZE / 4) + d4];
                    #pragma unroll
                    for (int dd = 0; dd < 4; ++dd) acc[qh] += qv[dd] * k[dd];
                }
            }
            const int g0 = c * CHUNK_TOK + t0;   // global token index
            #pragma unroll
            for (int qh = 0; qh < Q_PER_KV; ++qh) {
                v4f sv;
                #pragma unroll
                for (int j = 0; j < 4; ++j) {
                    const int g = g0 + j;
                    sv[j] = (g < ctx && g != last) ? acc[qh][j] : -FLT_MAX;
                }
                *reinterpret_cast<v4f*>(&s_lds[qh * CHUNK_TOK + t0]) = sv;
            }
        } else {
            const v4f mv = (v4f)(-FLT_MAX);
            #pragma unroll
            for (int qh = 0; qh < Q_PER_KV; ++qh)
                *reinterpret_cast<v4f*>(&s_lds[qh * CHUNK_TOK + t0]) = mv;
        }
    }
    __syncthreads();

    // ---- chunk-local softmax (un-normalized), one wave, qh sequential ----
    float* wsp = ws + (((size_t)b * NUM_KV_HEADS + h) * NCHUNK + c) * WS_STRIDE;
    #pragma unroll
    for (int qh = 0; qh < Q_PER_KV; ++qh) {
        float s0 = s_lds[qh * CHUNK_TOK + tid];
        float s1 = s_lds[qh * CHUNK_TOK + tid + 64];
        float s2 = s_lds[qh * CHUNK_TOK + tid + 128];
        float s3 = s_lds[qh * CHUNK_TOK + tid + 192];
        float m = fmaxf(fmaxf(s0, s1), fmaxf(s2, s3));
        #pragma unroll
        for (int off = 32; off; off >>= 1) m = fmaxf(m, __shfl_xor(m, off));
        float p0 = (s0 == -FLT_MAX) ? 0.f : __expf(s0 - m);
        float p1 = (s1 == -FLT_MAX) ? 0.f : __expf(s1 - m);
        float p2 = (s2 == -FLT_MAX) ? 0.f : __expf(s2 - m);
        float p3 = (s3 == -FLT_MAX) ? 0.f : __expf(s3 - m);
        s_lds[qh * CHUNK_TOK + tid]       = p0;
        s_lds[qh * CHUNK_TOK + tid + 64]  = p1;
        s_lds[qh * CHUNK_TOK + tid + 128] = p2;
        s_lds[qh * CHUNK_TOK + tid + 192] = p3;
        float l = p0 + p1 + p2 + p3;
        #pragma unroll
        for (int off = 32; off; off >>= 1) l += __shfl_xor(l, off);
        if (tid == 0) { ml_lds[qh] = m; ml_lds[Q_PER_KV + qh] = l; }
    }
    __syncthreads();
    if (tid < 2 * Q_PER_KV) wsp[tid] = ml_lds[tid];

    // ---- partial PV: lane handles dims {tid, tid+64} ----
    {
        const int d0 = tid, d1 = tid + 64;
        float acc0[Q_PER_KV] = {0.f, 0.f, 0.f, 0.f};
        float acc1[Q_PER_KV] = {0.f, 0.f, 0.f, 0.f};
        const int nbl = min(nb - cb, CHUNK_BLOCKS);
        for (int bil = 0; bil < nbl; ++bil) {
            const int phys = block_tables[b * MAX_BLOCKS + cb + bil];
            const v4f* vp = reinterpret_cast<const v4f*>(value_cache) +
                            ((size_t)phys * NUM_KV_HEADS + h) * (HEAD_SIZE * BLOCK_SZ / 4);
            v4f vv0[4], vv1[4];
            #pragma unroll
            for (int j = 0; j < 4; ++j) { vv0[j] = vp[d0 * 4 + j]; vv1[j] = vp[d1 * 4 + j]; }
            #pragma unroll
            for (int qh = 0; qh < Q_PER_KV; ++qh) {
                const v4f* pq = reinterpret_cast<const v4f*>(
                    &s_lds[qh * CHUNK_TOK + bil * BLOCK_SZ]);
                #pragma unroll
                for (int j = 0; j < 4; ++j) {
                    v4f p = pq[j];
                    acc0[qh] += p[0]*vv0[j][0] + p[1]*vv0[j][1] + p[2]*vv0[j][2] + p[3]*vv0[j][3];
                    acc1[qh] += p[0]*vv1[j][0] + p[1]*vv1[j][1] + p[2]*vv1[j][2] + p[3]*vv1[j][3];
                }
            }
        }
        float* wo = wsp + 2 * Q_PER_KV;
        #pragma unroll
        for (int qh = 0; qh < Q_PER_KV; ++qh) {
            wo[qh * HEAD_SIZE + d0] = acc0[qh];
            wo[qh * HEAD_SIZE + d1] = acc1[qh];
        }
    }
}

// ---------------- kernel 2: merge chunks + new token + normalize ----------------
// grid (NUM_KV_HEADS, BATCH), 512 threads.
__global__ __launch_bounds__(512, 2)
void paged_attn_reduce(const float* __restrict__ query,
                       const float* __restrict__ k_new,
                       const float* __restrict__ v_new,
                       const int* __restrict__ context_lens,
                       const float* __restrict__ ws,
                       float* __restrict__ out) {
    const int h   = blockIdx.x;
    const int b   = blockIdx.y;
    const int tid = threadIdx.x;

    __shared__ float snew_lds[Q_PER_KV];

    const int ctx = context_lens[b];
    const int nb  = (ctx + BLOCK_SZ - 1) / BLOCK_SZ;
    const int nch = (nb + CHUNK_BLOCKS - 1) / CHUNK_BLOCKS;

    // s_new[qh] = SCALE * q[qh] . k_new   (4 waves, one per qh)
    if (tid < 4 * 64) {
        const int w = tid >> 6, lane = tid & 63;
        const float* qp = query + ((size_t)b * NUM_HEADS + h * Q_PER_KV + w) * HEAD_SIZE;
        const float* kn = k_new + ((size_t)b * NUM_KV_HEADS + h) * HEAD_SIZE;
        float v = qp[lane] * kn[lane] + qp[lane + 64] * kn[lane + 64];
        #pragma unroll
        for (int off = 32; off; off >>= 1) v += __shfl_xor(v, off);
        if (lane == 0) snew_lds[w] = v * SCALE;
    }
    __syncthreads();

    const int qh = tid >> 7, d = tid & 127;
    const float* wsb = ws + ((size_t)b * NUM_KV_HEADS + h) * NCHUNK * WS_STRIDE;

    float M = -FLT_MAX, L = 0.f, acc = 0.f;
    for (int c = 0; c < nch; ++c) {
        const float* wsp = wsb + (size_t)c * WS_STRIDE;
        const float mc = wsp[qh];
        const float lc = wsp[Q_PER_KV + qh];
        const float oc = wsp[2 * Q_PER_KV + qh * HEAD_SIZE + d];
        const float nM = fmaxf(M, mc);
        const float eM = __expf(M - nM), ec = __expf(mc - nM);
        acc = acc * eM + oc * ec;
        L   = L   * eM + lc * ec;
        M   = nM;
    }
    // new token (exact, from k_new/v_new)
    {
        const float s  = snew_lds[qh];
        const float nM = fmaxf(M, s);
        const float eM = __expf(M - nM), es = __expf(s - nM);
        const float vn = v_new[((size_t)b * NUM_KV_HEADS + h) * HEAD_SIZE + d];
        acc = acc * eM + es * vn;
        L   = L   * eM + es;
    }
    out[((size_t)b * NUM_HEADS + h * Q_PER_KV + qh) * HEAD_SIZE + d] = acc / L;
}

extern "C" void kernel_launch(void* const* d_in, const int* in_sizes, int n_in,
                              void* d_out, int out_size, void* d_ws, size_t ws_size,
                              hipStream_t stream) {
    const float* query       = (const float*)d_in[0];
    const float* k_new       = (const float*)d_in[1];
    const float* v_new       = (const float*)d_in[2];
    const float* key_cache   = (const float*)d_in[3];
    const float* value_cache = (const float*)d_in[4];
    const int*   block_tables  = (const int*)d_in[5];
    const int*   context_lens  = (const int*)d_in[6];
    float* out = (float*)d_out;
    float* ws  = (float*)d_ws;

    const int batch = in_sizes[6];

    dim3 g1(NUM_KV_HEADS, batch, NCHUNK);
    paged_attn_chunk<<<g1, 64, 0, stream>>>(query, key_cache, value_cache,
                                            block_tables, context_lens, ws);
    dim3 g2(NUM_KV_HEADS, batch);
    paged_attn_reduce<<<g2, 512, 0, stream>>>(query, k_new, v_new,
                                              context_lens, ws, out);
}